// Round 4
// baseline (623.993 us; speedup 1.0000x reference)
//
#include <hip/hip_runtime.h>

typedef short s8v  __attribute__((ext_vector_type(8)));
typedef float f4v  __attribute__((ext_vector_type(4)));
typedef int   v4i  __attribute__((ext_vector_type(4)));
typedef float v4f  __attribute__((ext_vector_type(4)));
typedef int   v2i  __attribute__((ext_vector_type(2)));

#define NNODES 8192
#define FDIM   256
#define NJC    4          // j-chunks (split-K factor)
#define JLEN   2048       // columns-j per chunk
#define TROWS  64         // rows per block (keeps B-frag reuse x4, PB L2 traffic 512 MiB)
#define KSTEP  32         // k per step = one PB k-tile
#define NSTEP  64         // JLEN / KSTEP

__device__ __forceinline__ unsigned short f2bf(float f) {
    unsigned int x = __builtin_bit_cast(unsigned int, f);
    x += 0x7fffu + ((x >> 16) & 1u);
    return (unsigned short)(x >> 16);
}
// RTNE pack of 2 f32 -> 1 dword of 2 bf16
__device__ __forceinline__ int cvt_pk(float lo, float hi) {
    int r;
    asm("v_cvt_pk_bf16_f32 %0, %1, %2" : "=v"(r) : "v"(lo), "v"(hi));
    return r;
}

// Barrier WITHOUT vmcnt drain (R11): LDS visibility needs only lgkmcnt(0);
// vmem data-deps are compiler-waited. Keeps adj prefetch in flight.
__device__ __forceinline__ void barrier_lds_only() {
    asm volatile("s_waitcnt lgkmcnt(0)" ::: "memory");
    __builtin_amdgcn_s_barrier();
    asm volatile("" ::: "memory");
}

// ---------------- Kernel 0: fused WT + wv + ticket zero ----------------
__global__ __launch_bounds__(256) void prep_kernel(const float* __restrict__ W,
                                                   const float* __restrict__ a,
                                                   unsigned short* __restrict__ WT,
                                                   float* __restrict__ v1,
                                                   float* __restrict__ v2,
                                                   int* __restrict__ ticket) {
    if (blockIdx.x < 256) {
        if (blockIdx.x == 0 && threadIdx.x < 128) ticket[threadIdx.x] = 0;
        int idx = blockIdx.x * 256 + threadIdx.x;
        int r = idx >> 8, c = idx & 255;
        WT[c * 256 + r] = f2bf(W[r * 256 + c]);
    } else {
        __shared__ float r1[256], r2[256];
        int b = blockIdx.x - 256, n = threadIdx.x;
        float w = W[(size_t)b * FDIM + n];
        r1[n] = w * a[n];
        r2[n] = w * a[FDIM + n];
        __syncthreads();
        for (int off = 128; off > 0; off >>= 1) {
            if (n < off) { r1[n] += r1[n + off]; r2[n] += r2[n + off]; }
            __syncthreads();
        }
        if (n == 0) { v1[b] = r1[0]; v2[b] = r2[0]; }
    }
}

// ---------------- Kernel 1: PB = tiled bf16 Wh; s1/s2 = h@v (fp32) ----------------
// 256 blocks x 128 threads (R12: full CU coverage).
__global__ __launch_bounds__(128) void wh_kernel(
    const float* __restrict__ h, const unsigned short* __restrict__ WT,
    const float* __restrict__ v1, const float* __restrict__ v2,
    unsigned short* __restrict__ PB,
    float* __restrict__ s1, float* __restrict__ s2)
{
    __shared__ float v1_lds[FDIM], v2_lds[FDIM];
    int tid = threadIdx.x;
    v1_lds[tid] = v1[tid];       v1_lds[tid + 128] = v1[tid + 128];
    v2_lds[tid] = v2[tid];       v2_lds[tid + 128] = v2[tid + 128];
    __syncthreads();

    int w = tid >> 6, lane = tid & 63, q = lane >> 4, l15 = lane & 15;
    int i_base = blockIdx.x * 32 + w * 16;

    f4v acc[16] = {};
    float s1p = 0.f, s2p = 0.f;

    for (int k0 = 0; k0 < 256; k0 += 32) {
        const float* hp = h + (size_t)(i_base + l15) * FDIM + k0 + q * 8;
        f4v h0 = *(const f4v*)hp;
        f4v h1 = *(const f4v*)(hp + 4);
        union { v4i u; s8v s; } af;
        af.u[0] = cvt_pk(h0[0], h0[1]);
        af.u[1] = cvt_pk(h0[2], h0[3]);
        af.u[2] = cvt_pk(h1[0], h1[1]);
        af.u[3] = cvt_pk(h1[2], h1[3]);
#pragma unroll
        for (int j = 0; j < 4; ++j) {
            s1p += h0[j] * v1_lds[k0 + q * 8 + j] + h1[j] * v1_lds[k0 + q * 8 + 4 + j];
            s2p += h0[j] * v2_lds[k0 + q * 8 + j] + h1[j] * v2_lds[k0 + q * 8 + 4 + j];
        }
#pragma unroll
        for (int t = 0; t < 16; ++t) {
            s8v bf = *(const s8v*)(WT + (size_t)(t * 16 + l15) * FDIM + k0 + q * 8);
            acc[t] = __builtin_amdgcn_mfma_f32_16x16x32_bf16(af.s, bf, acc[t], 0, 0, 0);
        }
    }

    s1p += __shfl_xor(s1p, 16, 64);
    s1p += __shfl_xor(s1p, 32, 64);
    s2p += __shfl_xor(s2p, 16, 64);
    s2p += __shfl_xor(s2p, 32, 64);
    if (lane < 16) {
        s1[i_base + lane] = s1p;
        s2[i_base + lane] = s2p;
    }

#pragma unroll
    for (int t = 0; t < 16; ++t) {
        int i0 = i_base + q * 4;
        size_t a16 = (size_t)((i0 >> 5) * 16 + t) * 512
                   + l15 * 32 + ((i0 >> 3) & 3) * 8 + (i0 & 7);
        v2i pk;
        pk[0] = cvt_pk(acc[t][0], acc[t][1]);
        pk[1] = cvt_pk(acc[t][2], acc[t][3]);
        *(v2i*)(PB + a16) = pk;
    }
}

// ---------------- Kernel 2: split-K partial attention + fused reduce ----------------
// R13: 512-thread blocks (8 waves). Grid 512 = 128 rt x 4 jc -> 2 blocks/CU
// = 16 waves/CU = 4 waves/SIMD (R2's 256-thread version was grid-capped at
// 2 waves/SIMD). TROWS=64 keeps B-frag reuse x4. acc[4][2]=32 VGPR -> fits
// the 128-VGPR cap of (512,4). jc=bid&3: round-robin over 8 XCDs pins one
// 1-MiB PB slice per XCD (L2-resident). Last jc-block per rt (threadfence+
// ticket) reduces the 4 partials in-place -> reduce_kernel eliminated.
__global__ __launch_bounds__(512, 4) void attn_partial(
    const int* __restrict__ adj, const unsigned short* __restrict__ PB,
    const float* __restrict__ s1, const float* __restrict__ s2,
    float* __restrict__ Npart, float* __restrict__ dpart,
    int* __restrict__ ticket, float* __restrict__ out)
{
    __shared__ float s2_lds[JLEN];                      // 8 KB
    __shared__ unsigned short P_lds[2][TROWS * KSTEP];  // 2 x 4 KB
    __shared__ float dsum_lds[TROWS][8];                // 2 KB
    __shared__ int amLast;

    int tid = threadIdx.x;
    int jc = blockIdx.x & 3, rt = blockIdx.x >> 2;
    int j0 = jc * JLEN;

    // stage s2 (512 threads x 16B = 8 KB in one sweep)
    ((v4f*)s2_lds)[tid] = ((const v4f*)(s2 + j0))[tid];

    // P-generator role: row m 0..63, k-slice idx 0..7 (4 j's per thread/step)
    int m = tid >> 3, idx = tid & 7;
    int row_g = rt * TROWS + m;
    float s1v = s1[row_g];
    const int* arow = adj + (size_t)row_g * NNODES + j0 + idx * 4;
    int qw = idx >> 1, half = idx & 1;
    int woff = ((qw * 64 + m) * 8 + half * 4) ^ (qw * 16);

    // MFMA role: wave g (0..7) -> cols g*32 + tt*16 + l15; rowhalves rh 0..3
    int g = tid >> 6, lane = tid & 63, q = lane >> 4, l15 = lane & 15;
    const unsigned short* pbb = PB + (size_t)(jc * 64) * 16 * 512 + l15 * 32 + q * 8;

    f4v acc[4][2] = {};
    float dsum = 0.0f;

    __syncthreads();  // s2 staged

    // prologue: adj step0 used now; steps 1,2 parked (in-flight window ~2 steps)
    v4i p0 = __builtin_nontemporal_load((const v4i*)(arow));
    v4i a1 = __builtin_nontemporal_load((const v4i*)(arow + 1 * KSTEP));
    v4i a2 = __builtin_nontemporal_load((const v4i*)(arow + 2 * KSTEP));
    {
        v4f sv = *(const v4f*)&s2_lds[idx * 4];
        float pa[4];
#pragma unroll
        for (int j = 0; j < 4; ++j) {
            float x = s1v + sv[j];
            float p = (p0[j] > 0) ? __expf(fmaxf(x, 0.2f * x)) : 0.0f;
            pa[j] = p; dsum += p;
        }
        v2i pv;
        pv[0] = cvt_pk(pa[0], pa[1]);
        pv[1] = cvt_pk(pa[2], pa[3]);
        *(v2i*)&P_lds[0][woff] = pv;
    }
    barrier_lds_only();

    for (int s = 0; s < NSTEP; ++s) {
        // adj for step s+3 (stays in flight across lgkm-only barriers)
        int kn = (s < NSTEP - 3) ? (s + 3) * KSTEP : 0;
        v4i nx = __builtin_nontemporal_load((const v4i*)(arow + kn));

        // B-frags for step s: 2 KiB per wave, reused over 4 rowhalves
        s8v bf0 = *(const s8v*)(pbb + (size_t)(s * 16 + g * 2) * 512);
        s8v bf1 = *(const s8v*)(pbb + (size_t)(s * 16 + g * 2 + 1) * 512);

        // P for step s+1 from a1 (loaded 2 steps ago)
        if (s < NSTEP - 1) {
            v4f sv = *(const v4f*)&s2_lds[(s + 1) * KSTEP + idx * 4];
            float pa[4];
#pragma unroll
            for (int j = 0; j < 4; ++j) {
                float x = s1v + sv[j];
                float p = (a1[j] > 0) ? __expf(fmaxf(x, 0.2f * x)) : 0.0f;
                pa[j] = p; dsum += p;
            }
            v2i pv;
            pv[0] = cvt_pk(pa[0], pa[1]);
            pv[1] = cvt_pk(pa[2], pa[3]);
            *(v2i*)&P_lds[(s + 1) & 1][woff] = pv;
        }

        // MFMA over 4 rowhalves x 2 col-tiles
        const unsigned short* pbuf = P_lds[s & 1];
#pragma unroll
        for (int rh = 0; rh < 4; ++rh) {
            s8v af = *(const s8v*)&pbuf[((q * 64 + rh * 16 + l15) * 8) ^ (q * 16)];
            acc[rh][0] = __builtin_amdgcn_mfma_f32_16x16x32_bf16(af, bf0, acc[rh][0], 0, 0, 0);
            acc[rh][1] = __builtin_amdgcn_mfma_f32_16x16x32_bf16(af, bf1, acc[rh][1], 0, 0, 0);
        }

        barrier_lds_only();
        a1 = a2; a2 = nx;
    }

    // partial denominator
    dsum_lds[m][idx] = dsum;
    __syncthreads();
    if (tid < TROWS) {
        float d = 0.f;
#pragma unroll
        for (int k = 0; k < 8; ++k) d += dsum_lds[tid][k];
        dpart[jc * NNODES + rt * TROWS + tid] = d;
    }

    // partial numerator: row = rh*16 + q*4 + r, col = g*32 + tt*16 + l15
#pragma unroll
    for (int rh = 0; rh < 4; ++rh)
#pragma unroll
        for (int r = 0; r < 4; ++r) {
            int row = rh * 16 + q * 4 + r;
            float* base = Npart + ((size_t)(jc * NNODES) + rt * TROWS + row) * FDIM;
            base[g * 32 + l15]      = acc[rh][0][r];
            base[g * 32 + 16 + l15] = acc[rh][1][r];
        }

    // ---- fused reduce: last of the 4 jc-blocks for this rt normalizes ----
    __threadfence();          // release: Npart/dpart stores device-visible
    __syncthreads();
    if (tid == 0) amLast = (atomicAdd(&ticket[rt], 1) == NJC - 1);
    __syncthreads();
    if (amLast) {
        __threadfence();      // acquire: see other blocks' Npart/dpart
        if (tid < TROWS) {
            float dd = 0.f;
#pragma unroll
            for (int jcc = 0; jcc < NJC; ++jcc)
                dd += dpart[jcc * NNODES + rt * TROWS + tid];
            dsum_lds[tid][0] = dd;
        }
        __syncthreads();
        for (int e = tid; e < TROWS * FDIM; e += 512) {
            int row = e >> 8, col = e & 255;
            float sacc = 0.f;
#pragma unroll
            for (int jcc = 0; jcc < NJC; ++jcc)
                sacc += Npart[((size_t)(jcc * NNODES) + rt * TROWS + row) * FDIM + col];
            out[((size_t)(rt * TROWS + row)) * FDIM + col] =
                sacc / fmaxf(dsum_lds[row][0], 1e-30f);
        }
    }
}

extern "C" void kernel_launch(void* const* d_in, const int* in_sizes, int n_in,
                              void* d_out, int out_size, void* d_ws, size_t ws_size,
                              hipStream_t stream) {
    const float* h   = (const float*)d_in[0];
    const int*   adj = (const int*)d_in[1];
    const float* W   = (const float*)d_in[2];
    const float* a   = (const float*)d_in[3];
    float* out = (float*)d_out;

    char* ws = (char*)d_ws;
    unsigned short* PB = (unsigned short*)ws;                  // 4 MiB (tiled Wh)
    float* s1 = (float*)(ws + (4u << 20));                     // 32 KiB
    float* s2 = (float*)(ws + (4u << 20) + (32u << 10));       // 32 KiB
    unsigned short* WT = (unsigned short*)(ws + (4u << 20) + (64u << 10));   // 128 KiB
    float* v1 = (float*)(ws + (4u << 20) + (192u << 10));      // 1 KiB
    float* v2 = (float*)(ws + (4u << 20) + (193u << 10));      // 1 KiB
    float* dpart = (float*)(ws + (5u << 20));                  // 128 KiB
    int* ticket  = (int*)(ws + (5u << 20) + (128u << 10));     // 512 B
    float* Npart = (float*)(ws + (8u << 20));                  // 32 MiB

    hipLaunchKernelGGL(prep_kernel, dim3(512), dim3(256), 0, stream, W, a, WT, v1, v2, ticket);
    hipLaunchKernelGGL(wh_kernel, dim3(256), dim3(128), 0, stream, h, WT, v1, v2, PB, s1, s2);
    hipLaunchKernelGGL(attn_partial, dim3(128 * NJC), dim3(512), 0, stream,
                       adj, PB, s1, s2, Npart, dpart, ticket, out);
}

// Round 5
// 461.978 us; speedup vs baseline: 1.3507x; 1.3507x over previous
//
#include <hip/hip_runtime.h>

typedef short s8v  __attribute__((ext_vector_type(8)));
typedef float f4v  __attribute__((ext_vector_type(4)));
typedef int   v4i  __attribute__((ext_vector_type(4)));
typedef float v4f  __attribute__((ext_vector_type(4)));
typedef int   v2i  __attribute__((ext_vector_type(2)));

#define NNODES 8192
#define FDIM   256
#define NJC    2          // j-chunks (R14: 2 -> grid 256 = exactly 1 block/CU, halves Npart)
#define JLEN   4096       // columns-j per chunk
#define TROWS  64         // rows per block
#define KSTEP  32         // k per step = one PB k-tile
#define NSTEP  128        // JLEN / KSTEP

__device__ __forceinline__ unsigned short f2bf(float f) {
    unsigned int x = __builtin_bit_cast(unsigned int, f);
    x += 0x7fffu + ((x >> 16) & 1u);
    return (unsigned short)(x >> 16);
}
// RTNE pack of 2 f32 -> 1 dword of 2 bf16
__device__ __forceinline__ int cvt_pk(float lo, float hi) {
    int r;
    asm("v_cvt_pk_bf16_f32 %0, %1, %2" : "=v"(r) : "v"(lo), "v"(hi));
    return r;
}

// Barrier WITHOUT vmcnt drain: LDS visibility needs only lgkmcnt(0);
// vmem data-deps are compiler-waited per-wave.
__device__ __forceinline__ void barrier_lds_only() {
    asm volatile("s_waitcnt lgkmcnt(0)" ::: "memory");
    __builtin_amdgcn_s_barrier();
    asm volatile("" ::: "memory");
}

// ---------------- Kernel 0: fused WT + wv ----------------
__global__ __launch_bounds__(256) void prep_kernel(const float* __restrict__ W,
                                                   const float* __restrict__ a,
                                                   unsigned short* __restrict__ WT,
                                                   float* __restrict__ v1,
                                                   float* __restrict__ v2) {
    if (blockIdx.x < 256) {
        int idx = blockIdx.x * 256 + threadIdx.x;
        int r = idx >> 8, c = idx & 255;
        WT[c * 256 + r] = f2bf(W[r * 256 + c]);
    } else {
        __shared__ float r1[256], r2[256];
        int b = blockIdx.x - 256, n = threadIdx.x;
        float w = W[(size_t)b * FDIM + n];
        r1[n] = w * a[n];
        r2[n] = w * a[FDIM + n];
        __syncthreads();
        for (int off = 128; off > 0; off >>= 1) {
            if (n < off) { r1[n] += r1[n + off]; r2[n] += r2[n + off]; }
            __syncthreads();
        }
        if (n == 0) { v1[b] = r1[0]; v2[b] = r2[0]; }
    }
}

// ---------------- Kernel 1: PB = tiled bf16 Wh; s1/s2 = h@v (fp32) ----------------
// 256 blocks x 128 threads (R2 known-good).
__global__ __launch_bounds__(128) void wh_kernel(
    const float* __restrict__ h, const unsigned short* __restrict__ WT,
    const float* __restrict__ v1, const float* __restrict__ v2,
    unsigned short* __restrict__ PB,
    float* __restrict__ s1, float* __restrict__ s2)
{
    __shared__ float v1_lds[FDIM], v2_lds[FDIM];
    int tid = threadIdx.x;
    v1_lds[tid] = v1[tid];       v1_lds[tid + 128] = v1[tid + 128];
    v2_lds[tid] = v2[tid];       v2_lds[tid + 128] = v2[tid + 128];
    __syncthreads();

    int w = tid >> 6, lane = tid & 63, q = lane >> 4, l15 = lane & 15;
    int i_base = blockIdx.x * 32 + w * 16;

    f4v acc[16] = {};
    float s1p = 0.f, s2p = 0.f;

    for (int k0 = 0; k0 < 256; k0 += 32) {
        const float* hp = h + (size_t)(i_base + l15) * FDIM + k0 + q * 8;
        f4v h0 = *(const f4v*)hp;
        f4v h1 = *(const f4v*)(hp + 4);
        union { v4i u; s8v s; } af;
        af.u[0] = cvt_pk(h0[0], h0[1]);
        af.u[1] = cvt_pk(h0[2], h0[3]);
        af.u[2] = cvt_pk(h1[0], h1[1]);
        af.u[3] = cvt_pk(h1[2], h1[3]);
#pragma unroll
        for (int j = 0; j < 4; ++j) {
            s1p += h0[j] * v1_lds[k0 + q * 8 + j] + h1[j] * v1_lds[k0 + q * 8 + 4 + j];
            s2p += h0[j] * v2_lds[k0 + q * 8 + j] + h1[j] * v2_lds[k0 + q * 8 + 4 + j];
        }
#pragma unroll
        for (int t = 0; t < 16; ++t) {
            s8v bf = *(const s8v*)(WT + (size_t)(t * 16 + l15) * FDIM + k0 + q * 8);
            acc[t] = __builtin_amdgcn_mfma_f32_16x16x32_bf16(af.s, bf, acc[t], 0, 0, 0);
        }
    }

    s1p += __shfl_xor(s1p, 16, 64);
    s1p += __shfl_xor(s1p, 32, 64);
    s2p += __shfl_xor(s2p, 16, 64);
    s2p += __shfl_xor(s2p, 32, 64);
    if (lane < 16) {
        s1[i_base + lane] = s1p;
        s2[i_base + lane] = s2p;
    }

#pragma unroll
    for (int t = 0; t < 16; ++t) {
        int i0 = i_base + q * 4;
        size_t a16 = (size_t)((i0 >> 5) * 16 + t) * 512
                   + l15 * 32 + ((i0 >> 3) & 3) * 8 + (i0 & 7);
        v2i pk;
        pk[0] = cvt_pk(acc[t][0], acc[t][1]);
        pk[1] = cvt_pk(acc[t][2], acc[t][3]);
        *(v2i*)(PB + a16) = pk;
    }
}

// ---------------- Kernel 2: producer-consumer split-K attention ----------------
// R14: 512 threads = 4 CONSUMER waves (tid<256: bf loads + MFMA only) +
// 4 PRODUCER waves (tid>=256: adj loads + exp + P_lds writes only).
// vmcnt is PER-WAVE: consumer's counter stream holds only L2-hit bf loads
// (reg-double-buffered -> ~0 exposed wait); producer's holds only adj HBM
// loads, hidden by its own depth-3 parked prefetch. This removes R2-R4's
// FIFO coupling where the MFMA's bf-wait drained every in-flight adj load.
// Grid 256 = 128 rt x 2 jc = exactly 1 block/CU; (512,2) -> VGPR cap 256
// (union of both role live-sets ~165, no spills). jc=bid&1 pins one 2-MiB
// PB slice per XCD. Hand-off: double-buffered P_lds + lgkm-only barrier
// (same protocol as R2, proven race-free).
__global__ __launch_bounds__(512, 2) void attn_partial(
    const int* __restrict__ adj, const unsigned short* __restrict__ PB,
    const float* __restrict__ s1, const float* __restrict__ s2,
    float* __restrict__ Npart, float* __restrict__ dpart)
{
    __shared__ float s2_lds[JLEN];                      // 16 KB
    __shared__ unsigned short P_lds[2][TROWS * KSTEP];  // 2 x 4 KB
    __shared__ float dsum_lds[TROWS][4];                // 1 KB

    int tid = threadIdx.x;
    int jc = blockIdx.x & 1, rt = blockIdx.x >> 1;
    int j0 = jc * JLEN;

    // stage s2: 512 threads x 2 x 16B = 16 KB
    ((v4f*)s2_lds)[tid]       = ((const v4f*)(s2 + j0))[tid];
    ((v4f*)s2_lds)[tid + 512] = ((const v4f*)(s2 + j0))[tid + 512];

    bool producer = (tid >= 256);

    // producer decomposition: row m 0..63, k-slice idx 0..3, 8 j's/thread/step
    int p = tid & 255, m = p >> 2, idx = p & 3;
    int woff = ((idx * 64 + m) * 8) ^ (idx * 16);   // P_lds write addr (R2 swizzle)
    float s1v = 0.f;
    const int* arow = adj + (size_t)(rt * TROWS + m) * NNODES + j0 + idx * 8;
    v4i a1_0 = {}, a1_1 = {}, a2_0 = {}, a2_1 = {}, a3_0 = {}, a3_1 = {};

    // consumer decomposition: wave g 0..3 -> cols g*64 + t*16 + l15
    int g = tid >> 6, lane = tid & 63, q = lane >> 4, l15 = lane & 15;
    const unsigned short* pbb = PB + (size_t)(jc * NSTEP) * 16 * 512 + l15 * 32 + q * 8;
    f4v acc[4][4] = {};
    s8v bfA[4], bfB[4];
    float dsum = 0.f;

    __syncthreads();  // s2 staged

    if (producer) {
        s1v = s1[rt * TROWS + m];
        // adj[0] used now; adj[1..3] parked (3+ steps of per-wave slack)
        v4i c0 = __builtin_nontemporal_load((const v4i*)(arow));
        v4i c1 = __builtin_nontemporal_load((const v4i*)(arow + 4));
        a1_0 = __builtin_nontemporal_load((const v4i*)(arow + 1 * KSTEP));
        a1_1 = __builtin_nontemporal_load((const v4i*)(arow + 1 * KSTEP + 4));
        a2_0 = __builtin_nontemporal_load((const v4i*)(arow + 2 * KSTEP));
        a2_1 = __builtin_nontemporal_load((const v4i*)(arow + 2 * KSTEP + 4));
        a3_0 = __builtin_nontemporal_load((const v4i*)(arow + 3 * KSTEP));
        a3_1 = __builtin_nontemporal_load((const v4i*)(arow + 3 * KSTEP + 4));
        v4f sA = *(const v4f*)&s2_lds[idx * 8];
        v4f sB = *(const v4f*)&s2_lds[idx * 8 + 4];
        float pa[4], pb_[4];
#pragma unroll
        for (int j = 0; j < 4; ++j) {
            float x = s1v + sA[j];
            pa[j] = (c0[j] > 0) ? __expf(fmaxf(x, 0.2f * x)) : 0.0f; dsum += pa[j];
            float x2 = s1v + sB[j];
            pb_[j] = (c1[j] > 0) ? __expf(fmaxf(x2, 0.2f * x2)) : 0.0f; dsum += pb_[j];
        }
        v4i pv;
        pv[0] = cvt_pk(pa[0], pa[1]);
        pv[1] = cvt_pk(pa[2], pa[3]);
        pv[2] = cvt_pk(pb_[0], pb_[1]);
        pv[3] = cvt_pk(pb_[2], pb_[3]);
        *(v4i*)&P_lds[0][woff] = pv;
    } else {
        // preload step-0 B-frags
#pragma unroll
        for (int t = 0; t < 4; ++t)
            bfA[t] = *(const s8v*)(pbb + (size_t)(g * 4 + t) * 512);
    }
    barrier_lds_only();

// One pipeline step. BCUR: frags for step S (loaded one step ago);
// BNXT: issue loads for step S+1 (waited one step from now -> ~0 exposed).
#define STEP(S, BCUR, BNXT) do {                                              \
    if (!producer) {                                                          \
        int sn = ((S) + 1 < NSTEP) ? (S) + 1 : 0;                             \
        _Pragma("unroll")                                                     \
        for (int t = 0; t < 4; ++t)                                           \
            BNXT[t] = *(const s8v*)(pbb + (size_t)(sn * 16 + g * 4 + t) * 512);\
        const unsigned short* pbuf = P_lds[(S) & 1];                          \
        _Pragma("unroll")                                                     \
        for (int rh = 0; rh < 4; ++rh) {                                      \
            s8v af = *(const s8v*)&pbuf[((q * 64 + rh * 16 + l15) * 8) ^ (q * 16)]; \
            _Pragma("unroll")                                                 \
            for (int t = 0; t < 4; ++t)                                       \
                acc[rh][t] = __builtin_amdgcn_mfma_f32_16x16x32_bf16(af, BCUR[t], acc[rh][t], 0, 0, 0); \
        }                                                                     \
    } else {                                                                  \
        int kn = ((S) < NSTEP - 4) ? ((S) + 4) * KSTEP : 0;                   \
        v4i nx0 = __builtin_nontemporal_load((const v4i*)(arow + kn));        \
        v4i nx1 = __builtin_nontemporal_load((const v4i*)(arow + kn + 4));    \
        if ((S) < NSTEP - 1) {                                                \
            v4f sA = *(const v4f*)&s2_lds[((S) + 1) * KSTEP + idx * 8];       \
            v4f sB = *(const v4f*)&s2_lds[((S) + 1) * KSTEP + idx * 8 + 4];   \
            float pa[4], pb_[4];                                              \
            _Pragma("unroll")                                                 \
            for (int j = 0; j < 4; ++j) {                                     \
                float x = s1v + sA[j];                                        \
                pa[j] = (a1_0[j] > 0) ? __expf(fmaxf(x, 0.2f * x)) : 0.0f;    \
                dsum += pa[j];                                                \
                float x2 = s1v + sB[j];                                       \
                pb_[j] = (a1_1[j] > 0) ? __expf(fmaxf(x2, 0.2f * x2)) : 0.0f; \
                dsum += pb_[j];                                               \
            }                                                                 \
            v4i pv;                                                           \
            pv[0] = cvt_pk(pa[0], pa[1]);                                     \
            pv[1] = cvt_pk(pa[2], pa[3]);                                     \
            pv[2] = cvt_pk(pb_[0], pb_[1]);                                   \
            pv[3] = cvt_pk(pb_[2], pb_[3]);                                   \
            *(v4i*)&P_lds[((S) + 1) & 1][woff] = pv;                          \
        }                                                                     \
        a1_0 = a2_0; a1_1 = a2_1;                                             \
        a2_0 = a3_0; a2_1 = a3_1;                                             \
        a3_0 = nx0;  a3_1 = nx1;                                              \
    }                                                                         \
    barrier_lds_only();                                                       \
} while (0)

    for (int sb = 0; sb < NSTEP; sb += 2) {
        STEP(sb, bfA, bfB);
        STEP(sb + 1, bfB, bfA);
    }
#undef STEP

    // partial denominator (producers wrote dsum)
    if (producer) dsum_lds[m][idx] = dsum;
    __syncthreads();
    if (tid < TROWS) {
        float d = dsum_lds[tid][0] + dsum_lds[tid][1] + dsum_lds[tid][2] + dsum_lds[tid][3];
        dpart[jc * NNODES + rt * TROWS + tid] = d;
    }

    // partial numerator (consumers): row = rh*16 + q*4 + r, col = g*64 + t*16 + l15
    if (!producer) {
#pragma unroll
        for (int rh = 0; rh < 4; ++rh)
#pragma unroll
            for (int r = 0; r < 4; ++r) {
                int row = rh * 16 + q * 4 + r;
                float* base = Npart + ((size_t)(jc * NNODES) + rt * TROWS + row) * FDIM;
#pragma unroll
                for (int t = 0; t < 4; ++t)
                    __builtin_nontemporal_store(acc[rh][t][r], base + g * 64 + t * 16 + l15);
            }
    }
}

// ---------------- Kernel 3: reduce partials, normalize ----------------
__global__ __launch_bounds__(256) void reduce_kernel(
    const float* __restrict__ Npart, const float* __restrict__ dpart,
    float* __restrict__ out)
{
    int i = blockIdx.x, n = threadIdx.x;
    float d = 0.f, acc = 0.f;
#pragma unroll
    for (int jc = 0; jc < NJC; ++jc) {
        d += dpart[jc * NNODES + i];
        acc += Npart[((size_t)(jc * NNODES) + i) * FDIM + n];
    }
    out[(size_t)i * FDIM + n] = acc / fmaxf(d, 1e-30f);
}

extern "C" void kernel_launch(void* const* d_in, const int* in_sizes, int n_in,
                              void* d_out, int out_size, void* d_ws, size_t ws_size,
                              hipStream_t stream) {
    const float* h   = (const float*)d_in[0];
    const int*   adj = (const int*)d_in[1];
    const float* W   = (const float*)d_in[2];
    const float* a   = (const float*)d_in[3];
    float* out = (float*)d_out;

    char* ws = (char*)d_ws;
    unsigned short* PB = (unsigned short*)ws;                  // 4 MiB (tiled Wh)
    float* s1 = (float*)(ws + (4u << 20));                     // 32 KiB
    float* s2 = (float*)(ws + (4u << 20) + (32u << 10));       // 32 KiB
    unsigned short* WT = (unsigned short*)(ws + (4u << 20) + (64u << 10));   // 128 KiB
    float* v1 = (float*)(ws + (4u << 20) + (192u << 10));      // 1 KiB
    float* v2 = (float*)(ws + (4u << 20) + (193u << 10));      // 1 KiB
    float* dpart = (float*)(ws + (5u << 20));                  // 64 KiB
    float* Npart = (float*)(ws + (8u << 20));                  // 16 MiB

    hipLaunchKernelGGL(prep_kernel, dim3(512), dim3(256), 0, stream, W, a, WT, v1, v2);
    hipLaunchKernelGGL(wh_kernel, dim3(256), dim3(128), 0, stream, h, WT, v1, v2, PB, s1, s2);
    hipLaunchKernelGGL(attn_partial, dim3(128 * NJC), dim3(512), 0, stream,
                       adj, PB, s1, s2, Npart, dpart);
    hipLaunchKernelGGL(reduce_kernel, dim3(NNODES), dim3(256), 0, stream, Npart, dpart, out);
}